// Round 9
// baseline (2394.566 us; speedup 1.0000x reference)
//
#include <hip/hip_runtime.h>
#include <math.h>

#define NPTS 262144
#define D 128
#define KC 1024

typedef __bf16 bf16x8 __attribute__((ext_vector_type(8)));
typedef float floatx4 __attribute__((ext_vector_type(4)));

// async global->LDS, 16B per lane. LDS dest must be wave-uniform base (+lane*16 in HW).
__device__ __forceinline__ void async_copy16(const void* g, void* l) {
    __builtin_amdgcn_global_load_lds(
        (const __attribute__((address_space(1))) void*)g,
        (__attribute__((address_space(3))) void*)l, 16, 0, 0);
}

// ---------------- centroid norms + bf16 convert + counts zero ----------
__global__ void cc_kernel(const float* __restrict__ C, float* __restrict__ CC,
                          unsigned short* __restrict__ Cbf, int* __restrict__ counts) {
    const int row  = blockIdx.x;
    const int lane = threadIdx.x;
    float2 v = *(const float2*)(C + (size_t)row * D + lane * 2);
    __bf16 b0 = (__bf16)v.x, b1 = (__bf16)v.y;
    unsigned short u0, u1;
    __builtin_memcpy(&u0, &b0, 2);
    __builtin_memcpy(&u1, &b1, 2);
    ((ushort2*)Cbf)[(size_t)row * 64 + lane] = make_ushort2(u0, u1);
    float s = fmaf(v.x, v.x, v.y * v.y);
#pragma unroll
    for (int m = 1; m < 64; m <<= 1) s += __shfl_xor(s, m, 64);
    if (lane == 0) { CC[row] = s; counts[row] = 0; }   // grid == KC: zero counts here
}

// ---------------- assignment: LDS-staged bf16 MFMA + packed argmin ------
// 256 thr = 4 waves, BM=256 pts/block, mt=4. Plateau config (rounds 4-8):
// 2 blocks/CU, ~142us, FROZEN. Fused block histogram in the epilogue.
#define BM 256
#define KCH 64             // centroids per LDS chunk
#define NCH (KC / KCH)     // 16 chunks
#define CHB (KCH * D * 2)  // 16384 bytes per chunk

__device__ __forceinline__ void stage_chunk(const unsigned short* __restrict__ Cbf,
                                            unsigned short* buf, int chunk,
                                            int t, int w) {
    const char* gbase = (const char*)Cbf + (size_t)chunk * CHB;
    char* lbase = (char*)buf + w * 1024;   // wave-uniform; HW adds lane*16
#pragma unroll
    for (int it = 0; it < CHB / 4096; it++) {
        const int a   = it * 4096 + t * 16;     // linear byte offset in chunk
        const int row = a >> 8;                 // 0..63 (256 B per row)
        const int src = (row << 8) | ((a & 255) ^ ((row & 7) << 4));
        async_copy16(gbase + src, lbase + it * 4096);
    }
}

__global__ __launch_bounds__(256, 3) void assign_kernel(
    const float* __restrict__ X,
    const unsigned short* __restrict__ Cbf,
    const float* __restrict__ CC,
    int* __restrict__ y_hat,
    int* __restrict__ counts,
    float* __restrict__ inertia)
{
    __shared__ __align__(16) unsigned short Bs[2][KCH * D];  // 2 x 16 KB
    __shared__ float CCs[KC];   // 4 KB
    __shared__ float xxs[BM];   // 1 KB
    __shared__ int   hh[KC];    // 4 KB fused histogram

    const int t    = threadIdx.x;
    const int w    = t >> 6;
    const int lane = t & 63;
    const int m16  = lane & 15;
    const int quad = lane >> 4;
    const int pbase = blockIdx.x * BM;

    for (int i = t; i < KC; i += 256) { CCs[i] = CC[i]; hh[i] = 0; }

    // kick off chunk-0 staging early: overlaps the X/afrag HBM phase
    stage_chunk(Cbf, Bs[0], 0, t, w);

    // ---- A fragments (bf16) + exact fp32 ||x||^2 ----
    bf16x8 afrag[4][4];
#pragma unroll
    for (int mt = 0; mt < 4; mt++) {
        const int p = pbase + w * 64 + mt * 16 + m16;
        const float* xr = X + (size_t)p * D;
        float xp = 0.f;
#pragma unroll
        for (int ks = 0; ks < 4; ks++) {
            const int d0 = ks * 32 + quad * 8;
            float4 u0 = *(const float4*)(xr + d0);
            float4 u1 = *(const float4*)(xr + d0 + 4);
            xp = fmaf(u0.x, u0.x, xp); xp = fmaf(u0.y, u0.y, xp);
            xp = fmaf(u0.z, u0.z, xp); xp = fmaf(u0.w, u0.w, xp);
            xp = fmaf(u1.x, u1.x, xp); xp = fmaf(u1.y, u1.y, xp);
            xp = fmaf(u1.z, u1.z, xp); xp = fmaf(u1.w, u1.w, xp);
            bf16x8 f;
            f[0] = (__bf16)u0.x; f[1] = (__bf16)u0.y; f[2] = (__bf16)u0.z; f[3] = (__bf16)u0.w;
            f[4] = (__bf16)u1.x; f[5] = (__bf16)u1.y; f[6] = (__bf16)u1.z; f[7] = (__bf16)u1.w;
            afrag[mt][ks] = f;
        }
        xp += __shfl_xor(xp, 16, 64);
        xp += __shfl_xor(xp, 32, 64);
        if (quad == 0) xxs[w * 64 + mt * 16 + m16] = xp;
    }

    // packed running min: value in high bits, global step index in low 6
    float best[4][4];
#pragma unroll
    for (int mt = 0; mt < 4; mt++)
#pragma unroll
        for (int r = 0; r < 4; r++) best[mt][r] = 3.4e38f;

    __syncthreads();   // chunk-0 staged (vmcnt drained), CCs + hh ready

    for (int ch = 0; ch < NCH; ch++) {
        // prefetch next chunk into the other buffer (drained by end-barrier)
        if (ch + 1 < NCH) stage_chunk(Cbf, Bs[(ch + 1) & 1], ch + 1, t, w);

        const char* bufc = (const char*)Bs[ch & 1];
#pragma unroll
        for (int s = 0; s < KCH / 16; s++) {
            const int row  = s * 16 + m16;
            const int rswz = (row & 7) << 4;
            const char* rb = bufc + row * 256;

            floatx4 accs[4];
#pragma unroll
            for (int mt = 0; mt < 4; mt++) accs[mt] = (floatx4){0.f, 0.f, 0.f, 0.f};

            // two half-passes of (2 ds_read + 8 MFMA): bounds b-frag pressure
#pragma unroll
            for (int kh = 0; kh < 2; kh++) {
                bf16x8 b0 = *(const bf16x8*)(rb + ((quad * 16 + (kh * 2 + 0) * 64) ^ rswz));
                bf16x8 b1 = *(const bf16x8*)(rb + ((quad * 16 + (kh * 2 + 1) * 64) ^ rswz));
#pragma unroll
                for (int mt = 0; mt < 4; mt++)
                    accs[mt] = __builtin_amdgcn_mfma_f32_16x16x32_bf16(
                        afrag[mt][kh * 2 + 0], b0, accs[mt], 0, 0, 0);
#pragma unroll
                for (int mt = 0; mt < 4; mt++)
                    accs[mt] = __builtin_amdgcn_mfma_f32_16x16x32_bf16(
                        afrag[mt][kh * 2 + 1], b1, accs[mt], 0, 0, 0);
            }

            const int g = ch * (KCH / 16) + s;   // global step 0..63
            const float ccv = CCs[g * 16 + m16];
#pragma unroll
            for (int mt = 0; mt < 4; mt++)
#pragma unroll
                for (int r = 0; r < 4; r++) {
                    float d2 = fmaf(-2.f, accs[mt][r], ccv);
                    unsigned ub = (__float_as_uint(d2) & ~63u) | (unsigned)g;
                    best[mt][r] = fminf(best[mt][r], __uint_as_float(ub));
                }
        }
        if (ch + 1 < NCH) __syncthreads();  // drains prefetch; protects buffer reuse
    }

    // ---- unpack + cross-lane argmin + y_hat write + LDS histogram ----
    float part = 0.f;
#pragma unroll
    for (int mt = 0; mt < 4; mt++)
#pragma unroll
        for (int r = 0; r < 4; r++) {
            const unsigned ub = __float_as_uint(best[mt][r]);
            int   k = (int)(ub & 63u) * 16 + m16;
            float b = __uint_as_float(ub & ~63u);
#pragma unroll
            for (int m = 1; m < 16; m <<= 1) {
                float ob = __shfl_xor(b, m, 64);
                int   ok = __shfl_xor(k, m, 64);
                if (ob < b || (ob == b && ok < k)) { b = ob; k = ok; }
            }
            if (m16 == 0) {
                const int row = quad * 4 + r;
                const int p = pbase + w * 64 + mt * 16 + row;
                y_hat[p] = k;
                atomicAdd(&hh[k], 1);
                const float xx = xxs[w * 64 + mt * 16 + row];
                part += sqrtf(fmaxf(xx + b, 0.f));
            }
        }
#pragma unroll
    for (int m = 1; m < 64; m <<= 1) part += __shfl_xor(part, m, 64);
    if (lane == 0) atomicAdd(inertia, part);

    // ---- sparse flush of the fused histogram ----
    __syncthreads();
    for (int i = t; i < KC; i += 256) {
        int v = hh[i];
        if (v) atomicAdd(&counts[i], v);
    }
}

// ---------------- exclusive scan ----------------
__global__ void scan_kernel(const int* __restrict__ counts, int* __restrict__ cursor) {
    __shared__ int tmp[KC];
    int t = threadIdx.x;
    tmp[t] = counts[t];
    __syncthreads();
    for (int off = 1; off < KC; off <<= 1) {
        int v = tmp[t];
        int add = (t >= off) ? tmp[t - off] : 0;
        __syncthreads();
        tmp[t] = v + add;
        __syncthreads();
    }
    cursor[t] = (t == 0) ? 0 : tmp[t - 1];
}

// ---------------- scatter: LDS-rank, one cursor bump per (block,bin) -----
#define SPB 2048   // points per scatter block
__global__ __launch_bounds__(256) void scatter_kernel(
    const int* __restrict__ y_hat,
    int* __restrict__ cursor,
    int* __restrict__ order)
{
    __shared__ int h[KC];
    const int t = threadIdx.x;
    const int base_i = blockIdx.x * SPB;
    for (int i = t; i < KC; i += 256) h[i] = 0;
    __syncthreads();
    int myk[SPB / 256], myr[SPB / 256];
#pragma unroll
    for (int j = 0; j < SPB / 256; j++) {
        int k = y_hat[base_i + j * 256 + t];
        myk[j] = k;
        myr[j] = atomicAdd(&h[k], 1);
    }
    __syncthreads();
    for (int b = t; b < KC; b += 256) {
        int c = h[b];
        if (c) h[b] = atomicAdd(&cursor[b], c);   // reuse h[] as base[]
    }
    __syncthreads();
#pragma unroll
    for (int j = 0; j < SPB / 256; j++)
        order[h[myk[j]] + myr[j]] = base_i + j * 256 + t;
}

// ---------------- segmented reduction: one block per cluster, no atomics --
// Block k owns cluster k: reads its [cursor[k], cursor[k]+counts[k]) slice
// of order, gathers X/W rows (d = t&127, 2 point-streams, depth-4 rolling
// prefetch -- the r7-proven inner shape), accumulates in registers, LDS-
// combines the two streams, plain-stores w_sum[k]/xw_sum[k]. Zero global
// atomics, zero flush branches (r8's float4 version had wave-divergent
// flushes + 4x atomics -> +55us regression; reverted & de-atomized).
__global__ __launch_bounds__(256) void segsum_kernel(
    const float* __restrict__ X, const float* __restrict__ W,
    const int* __restrict__ order, const int* __restrict__ cursor,
    const int* __restrict__ counts,
    float* __restrict__ w_sum, float* __restrict__ xw_sum)
{
    const int k = blockIdx.x;
    const int n = counts[k];
    if (n == 0) return;                 // outputs pre-zeroed by memset
    const int start = cursor[k];
    const int t = threadIdx.x;
    const int d = t & 127;
    const int g = t >> 7;               // 2 point streams: g, g+2, ...

    float xs[4], wv[4];
#pragma unroll
    for (int j = 0; j < 4; j++) {
        int idx = g + 2 * j;
        if (idx < n) {
            int p = order[start + idx];
            xs[j] = X[(size_t)p * D + d];
            wv[j] = W[(size_t)p * D + d];
        } else { xs[j] = 0.f; wv[j] = 0.f; }
    }

    float wacc = 0.f, xwacc = 0.f;
#pragma unroll 4
    for (int i = g; i < n; i += 2) {
        float xn = 0.f, wn = 0.f;
        if (i + 8 < n) {
            int p = order[start + i + 8];
            xn = X[(size_t)p * D + d];
            wn = W[(size_t)p * D + d];
        }
        wacc += wv[0];
        xwacc = fmaf(xs[0], wv[0], xwacc);
        xs[0] = xs[1]; xs[1] = xs[2]; xs[2] = xs[3]; xs[3] = xn;
        wv[0] = wv[1]; wv[1] = wv[2]; wv[2] = wv[3]; wv[3] = wn;
    }

    __shared__ float sw[256], sxw[256];
    sw[t] = wacc; sxw[t] = xwacc;
    __syncthreads();
    if (t < 128) {
        w_sum [(size_t)k * D + t] = sw[t]  + sw[t + 128];
        xw_sum[(size_t)k * D + t] = sxw[t] + sxw[t + 128];
    }
}

extern "C" void kernel_launch(void* const* d_in, const int* in_sizes, int n_in,
                              void* d_out, int out_size, void* d_ws, size_t ws_size,
                              hipStream_t stream) {
    const float* X = (const float*)d_in[0];
    const float* W = (const float*)d_in[1];
    const float* C = (const float*)d_in[2];

    float* out     = (float*)d_out;
    float* inertia = out;
    float* w_sum   = out + 1;
    float* xw_sum  = out + 1 + KC * D;

    int*   y_hat  = (int*)d_ws;
    int*   order  = y_hat + NPTS;
    int*   counts = order + NPTS;
    int*   cursor = counts + KC;
    float* CC     = (float*)(cursor + KC);
    unsigned short* Cbf = (unsigned short*)(CC + KC);   // 1024*128 bf16, 16B-aligned

    hipMemsetAsync(d_out, 0, (size_t)out_size * sizeof(float), stream);

    cc_kernel<<<KC, 64, 0, stream>>>(C, CC, Cbf, counts);
    assign_kernel<<<NPTS / BM, 256, 0, stream>>>(X, Cbf, CC, y_hat, counts, inertia);
    scan_kernel<<<1, KC, 0, stream>>>(counts, cursor);
    scatter_kernel<<<NPTS / SPB, 256, 0, stream>>>(y_hat, cursor, order);
    segsum_kernel<<<KC, 256, 0, stream>>>(X, W, order, cursor, counts, w_sum, xw_sum);
}

// Round 10
// 395.340 us; speedup vs baseline: 6.0570x; 6.0570x over previous
//
#include <hip/hip_runtime.h>
#include <math.h>

#define NPTS 262144
#define D 128
#define KC 1024

typedef __bf16 bf16x8 __attribute__((ext_vector_type(8)));
typedef float floatx4 __attribute__((ext_vector_type(4)));

// async global->LDS, 16B per lane. LDS dest must be wave-uniform base (+lane*16 in HW).
__device__ __forceinline__ void async_copy16(const void* g, void* l) {
    __builtin_amdgcn_global_load_lds(
        (const __attribute__((address_space(1))) void*)g,
        (__attribute__((address_space(3))) void*)l, 16, 0, 0);
}

// ---------------- centroid norms + bf16 convert + counts zero ----------
__global__ void cc_kernel(const float* __restrict__ C, float* __restrict__ CC,
                          unsigned short* __restrict__ Cbf, int* __restrict__ counts) {
    const int row  = blockIdx.x;
    const int lane = threadIdx.x;
    float2 v = *(const float2*)(C + (size_t)row * D + lane * 2);
    __bf16 b0 = (__bf16)v.x, b1 = (__bf16)v.y;
    unsigned short u0, u1;
    __builtin_memcpy(&u0, &b0, 2);
    __builtin_memcpy(&u1, &b1, 2);
    ((ushort2*)Cbf)[(size_t)row * 64 + lane] = make_ushort2(u0, u1);
    float s = fmaf(v.x, v.x, v.y * v.y);
#pragma unroll
    for (int m = 1; m < 64; m <<= 1) s += __shfl_xor(s, m, 64);
    if (lane == 0) { CC[row] = s; counts[row] = 0; }   // grid == KC: zero counts here
}

// ---------------- assignment: LDS-staged bf16 MFMA + packed argmin ------
// 256 thr = 4 waves, BM=256 pts/block, mt=4. Plateau config (rounds 4-8):
// 2 blocks/CU, ~142us, FROZEN. Fused block histogram in the epilogue.
#define BM 256
#define KCH 64             // centroids per LDS chunk
#define NCH (KC / KCH)     // 16 chunks
#define CHB (KCH * D * 2)  // 16384 bytes per chunk

__device__ __forceinline__ void stage_chunk(const unsigned short* __restrict__ Cbf,
                                            unsigned short* buf, int chunk,
                                            int t, int w) {
    const char* gbase = (const char*)Cbf + (size_t)chunk * CHB;
    char* lbase = (char*)buf + w * 1024;   // wave-uniform; HW adds lane*16
#pragma unroll
    for (int it = 0; it < CHB / 4096; it++) {
        const int a   = it * 4096 + t * 16;     // linear byte offset in chunk
        const int row = a >> 8;                 // 0..63 (256 B per row)
        const int src = (row << 8) | ((a & 255) ^ ((row & 7) << 4));
        async_copy16(gbase + src, lbase + it * 4096);
    }
}

__global__ __launch_bounds__(256, 3) void assign_kernel(
    const float* __restrict__ X,
    const unsigned short* __restrict__ Cbf,
    const float* __restrict__ CC,
    int* __restrict__ y_hat,
    int* __restrict__ counts,
    float* __restrict__ inertia)
{
    __shared__ __align__(16) unsigned short Bs[2][KCH * D];  // 2 x 16 KB
    __shared__ float CCs[KC];   // 4 KB
    __shared__ float xxs[BM];   // 1 KB
    __shared__ int   hh[KC];    // 4 KB fused histogram

    const int t    = threadIdx.x;
    const int w    = t >> 6;
    const int lane = t & 63;
    const int m16  = lane & 15;
    const int quad = lane >> 4;
    const int pbase = blockIdx.x * BM;

    for (int i = t; i < KC; i += 256) { CCs[i] = CC[i]; hh[i] = 0; }

    // kick off chunk-0 staging early: overlaps the X/afrag HBM phase
    stage_chunk(Cbf, Bs[0], 0, t, w);

    // ---- A fragments (bf16) + exact fp32 ||x||^2 ----
    bf16x8 afrag[4][4];
#pragma unroll
    for (int mt = 0; mt < 4; mt++) {
        const int p = pbase + w * 64 + mt * 16 + m16;
        const float* xr = X + (size_t)p * D;
        float xp = 0.f;
#pragma unroll
        for (int ks = 0; ks < 4; ks++) {
            const int d0 = ks * 32 + quad * 8;
            float4 u0 = *(const float4*)(xr + d0);
            float4 u1 = *(const float4*)(xr + d0 + 4);
            xp = fmaf(u0.x, u0.x, xp); xp = fmaf(u0.y, u0.y, xp);
            xp = fmaf(u0.z, u0.z, xp); xp = fmaf(u0.w, u0.w, xp);
            xp = fmaf(u1.x, u1.x, xp); xp = fmaf(u1.y, u1.y, xp);
            xp = fmaf(u1.z, u1.z, xp); xp = fmaf(u1.w, u1.w, xp);
            bf16x8 f;
            f[0] = (__bf16)u0.x; f[1] = (__bf16)u0.y; f[2] = (__bf16)u0.z; f[3] = (__bf16)u0.w;
            f[4] = (__bf16)u1.x; f[5] = (__bf16)u1.y; f[6] = (__bf16)u1.z; f[7] = (__bf16)u1.w;
            afrag[mt][ks] = f;
        }
        xp += __shfl_xor(xp, 16, 64);
        xp += __shfl_xor(xp, 32, 64);
        if (quad == 0) xxs[w * 64 + mt * 16 + m16] = xp;
    }

    // packed running min: value in high bits, global step index in low 6
    float best[4][4];
#pragma unroll
    for (int mt = 0; mt < 4; mt++)
#pragma unroll
        for (int r = 0; r < 4; r++) best[mt][r] = 3.4e38f;

    __syncthreads();   // chunk-0 staged (vmcnt drained), CCs + hh ready

    for (int ch = 0; ch < NCH; ch++) {
        // prefetch next chunk into the other buffer (drained by end-barrier)
        if (ch + 1 < NCH) stage_chunk(Cbf, Bs[(ch + 1) & 1], ch + 1, t, w);

        const char* bufc = (const char*)Bs[ch & 1];
#pragma unroll
        for (int s = 0; s < KCH / 16; s++) {
            const int row  = s * 16 + m16;
            const int rswz = (row & 7) << 4;
            const char* rb = bufc + row * 256;

            floatx4 accs[4];
#pragma unroll
            for (int mt = 0; mt < 4; mt++) accs[mt] = (floatx4){0.f, 0.f, 0.f, 0.f};

            // two half-passes of (2 ds_read + 8 MFMA): bounds b-frag pressure
#pragma unroll
            for (int kh = 0; kh < 2; kh++) {
                bf16x8 b0 = *(const bf16x8*)(rb + ((quad * 16 + (kh * 2 + 0) * 64) ^ rswz));
                bf16x8 b1 = *(const bf16x8*)(rb + ((quad * 16 + (kh * 2 + 1) * 64) ^ rswz));
#pragma unroll
                for (int mt = 0; mt < 4; mt++)
                    accs[mt] = __builtin_amdgcn_mfma_f32_16x16x32_bf16(
                        afrag[mt][kh * 2 + 0], b0, accs[mt], 0, 0, 0);
#pragma unroll
                for (int mt = 0; mt < 4; mt++)
                    accs[mt] = __builtin_amdgcn_mfma_f32_16x16x32_bf16(
                        afrag[mt][kh * 2 + 1], b1, accs[mt], 0, 0, 0);
            }

            const int g = ch * (KCH / 16) + s;   // global step 0..63
            const float ccv = CCs[g * 16 + m16];
#pragma unroll
            for (int mt = 0; mt < 4; mt++)
#pragma unroll
                for (int r = 0; r < 4; r++) {
                    float d2 = fmaf(-2.f, accs[mt][r], ccv);
                    unsigned ub = (__float_as_uint(d2) & ~63u) | (unsigned)g;
                    best[mt][r] = fminf(best[mt][r], __uint_as_float(ub));
                }
        }
        if (ch + 1 < NCH) __syncthreads();  // drains prefetch; protects buffer reuse
    }

    // ---- unpack + cross-lane argmin + y_hat write + LDS histogram ----
    float part = 0.f;
#pragma unroll
    for (int mt = 0; mt < 4; mt++)
#pragma unroll
        for (int r = 0; r < 4; r++) {
            const unsigned ub = __float_as_uint(best[mt][r]);
            int   k = (int)(ub & 63u) * 16 + m16;
            float b = __uint_as_float(ub & ~63u);
#pragma unroll
            for (int m = 1; m < 16; m <<= 1) {
                float ob = __shfl_xor(b, m, 64);
                int   ok = __shfl_xor(k, m, 64);
                if (ob < b || (ob == b && ok < k)) { b = ob; k = ok; }
            }
            if (m16 == 0) {
                const int row = quad * 4 + r;
                const int p = pbase + w * 64 + mt * 16 + row;
                y_hat[p] = k;
                atomicAdd(&hh[k], 1);
                const float xx = xxs[w * 64 + mt * 16 + row];
                part += sqrtf(fmaxf(xx + b, 0.f));
            }
        }
#pragma unroll
    for (int m = 1; m < 64; m <<= 1) part += __shfl_xor(part, m, 64);
    if (lane == 0) atomicAdd(inertia, part);

    // ---- sparse flush of the fused histogram ----
    __syncthreads();
    for (int i = t; i < KC; i += 256) {
        int v = hh[i];
        if (v) atomicAdd(&counts[i], v);
    }
}

// ---------------- exclusive scan ----------------
__global__ void scan_kernel(const int* __restrict__ counts, int* __restrict__ cursor) {
    __shared__ int tmp[KC];
    int t = threadIdx.x;
    tmp[t] = counts[t];
    __syncthreads();
    for (int off = 1; off < KC; off <<= 1) {
        int v = tmp[t];
        int add = (t >= off) ? tmp[t - off] : 0;
        __syncthreads();
        tmp[t] = v + add;
        __syncthreads();
    }
    cursor[t] = (t == 0) ? 0 : tmp[t - 1];
}

// ---------------- scatter: LDS-rank, one cursor bump per (block,bin) -----
#define SPB 2048   // points per scatter block
__global__ __launch_bounds__(256) void scatter_kernel(
    const int* __restrict__ y_hat,
    int* __restrict__ cursor,
    int* __restrict__ order)
{
    __shared__ int h[KC];
    const int t = threadIdx.x;
    const int base_i = blockIdx.x * SPB;
    for (int i = t; i < KC; i += 256) h[i] = 0;
    __syncthreads();
    int myk[SPB / 256], myr[SPB / 256];
#pragma unroll
    for (int j = 0; j < SPB / 256; j++) {
        int k = y_hat[base_i + j * 256 + t];
        myk[j] = k;
        myr[j] = atomicAdd(&h[k], 1);
    }
    __syncthreads();
    for (int b = t; b < KC; b += 256) {
        int c = h[b];
        if (c) h[b] = atomicAdd(&cursor[b], c);   // reuse h[] as base[]
    }
    __syncthreads();
#pragma unroll
    for (int j = 0; j < SPB / 256; j++)
        order[h[myk[j]] + myr[j]] = base_i + j * 256 + t;
}

// ---------------- segmented reduction: slice-based, depth-4 prefetch ----
// r7-proven form, restored. One block per 256 consecutive `order` entries:
// skew-immune by construction (r9's one-block-per-cluster hit extreme
// cluster-size skew -> 1.6% occupancy, 2154us; and read cursor AFTER
// scatter consumed it -> wrong slices). Indices staged in LDS so the
// gather has no dependent global->global chain.
#define PPB 256
__global__ __launch_bounds__(256) void segsum_kernel(
    const float* __restrict__ X, const float* __restrict__ W,
    const int* __restrict__ order, const int* __restrict__ y_hat,
    float* __restrict__ w_sum, float* __restrict__ xw_sum)
{
    __shared__ int ps[PPB];
    __shared__ int kk[PPB];
    const int t = threadIdx.x;
    const int i0 = blockIdx.x * PPB;
    {
        int p = order[i0 + t];
        ps[t] = p;
        kk[t] = y_hat[p];
    }
    __syncthreads();

    const int d = t & 127;
    const int g = t >> 7;    // half: points g, g+2, ...

    float xs[4], wv[4];
#pragma unroll
    for (int j = 0; j < 4; j++) {
        int p = ps[g + 2 * j];
        xs[j] = X[(size_t)p * D + d];
        wv[j] = W[(size_t)p * D + d];
    }

    float wacc = 0.f, xwacc = 0.f;
    int cur = -1;

#pragma unroll 4
    for (int i = g; i < PPB; i += 2) {
        float xn = 0.f, wn = 0.f;
        if (i + 8 < PPB) {
            int p = ps[i + 8];
            xn = X[(size_t)p * D + d];
            wn = W[(size_t)p * D + d];
        }
        int k = kk[i];
        if (k != cur) {
            if (cur >= 0) {
                atomicAdd(&w_sum[(size_t)cur * D + d], wacc);
                atomicAdd(&xw_sum[(size_t)cur * D + d], xwacc);
            }
            cur = k; wacc = 0.f; xwacc = 0.f;
        }
        wacc += wv[0];
        xwacc = fmaf(xs[0], wv[0], xwacc);
        xs[0] = xs[1]; xs[1] = xs[2]; xs[2] = xs[3]; xs[3] = xn;
        wv[0] = wv[1]; wv[1] = wv[2]; wv[2] = wv[3]; wv[3] = wn;
    }
    if (cur >= 0) {
        atomicAdd(&w_sum[(size_t)cur * D + d], wacc);
        atomicAdd(&xw_sum[(size_t)cur * D + d], xwacc);
    }
}

extern "C" void kernel_launch(void* const* d_in, const int* in_sizes, int n_in,
                              void* d_out, int out_size, void* d_ws, size_t ws_size,
                              hipStream_t stream) {
    const float* X = (const float*)d_in[0];
    const float* W = (const float*)d_in[1];
    const float* C = (const float*)d_in[2];

    float* out     = (float*)d_out;
    float* inertia = out;
    float* w_sum   = out + 1;
    float* xw_sum  = out + 1 + KC * D;

    int*   y_hat  = (int*)d_ws;
    int*   order  = y_hat + NPTS;
    int*   counts = order + NPTS;
    int*   cursor = counts + KC;
    float* CC     = (float*)(cursor + KC);
    unsigned short* Cbf = (unsigned short*)(CC + KC);   // 1024*128 bf16, 16B-aligned

    hipMemsetAsync(d_out, 0, (size_t)out_size * sizeof(float), stream);

    cc_kernel<<<KC, 64, 0, stream>>>(C, CC, Cbf, counts);
    assign_kernel<<<NPTS / BM, 256, 0, stream>>>(X, Cbf, CC, y_hat, counts, inertia);
    scan_kernel<<<1, KC, 0, stream>>>(counts, cursor);
    scatter_kernel<<<NPTS / SPB, 256, 0, stream>>>(y_hat, cursor, order);
    segsum_kernel<<<NPTS / PPB, 256, 0, stream>>>(X, W, order, y_hat, w_sum, xw_sum);
}